// Round 11
// baseline (174.832 us; speedup 1.0000x reference)
//
#include <hip/hip_runtime.h>
#include <hip/hip_bf16.h>
#include <math.h>

#define N_NODES 50000
#define E_EDGES 800000
#define IN_DIM  128
#define HD      128   // H*D
#define SQRT_D_INV 0.25f

#define HIST_BLOCKS 1024                    // 256 thr; tid stride 2^18; c=(e&262143)>>15
#define NT          3125                    // 50000/16 row tiles (exact)
#define PROJ_WAVES  (NT * 6)                // (tile, which, half) units = 18750
#define PROJ_BLOCKS ((PROJ_WAVES + 3) / 4)  // 4688

typedef __attribute__((ext_vector_type(8))) short short8v;
typedef __attribute__((ext_vector_type(4))) float float4v;

__device__ inline unsigned short f2bf(float x) {
    __hip_bfloat16 b = __float2bfloat16(x);
    return *reinterpret_cast<unsigned short*>(&b);
}
__device__ inline float bflo(unsigned int u) { return __uint_as_float(u << 16); }
__device__ inline float bfhi(unsigned int u) { return __uint_as_float(u & 0xffff0000u); }

// ---------------- W transpose+convert + zero counts8 ----------------
__global__ __launch_bounds__(256) void wtr_init_kernel(
    const float* __restrict__ Qw, const float* __restrict__ Kw, const float* __restrict__ Vw,
    unsigned short* __restrict__ wt, int* __restrict__ counts8)
{
    int i = blockIdx.x * 256 + threadIdx.x;          // 392*256 = 100352 threads
    for (int j = i; j <= 8 * N_NODES; j += 392 * 256) counts8[j] = 0;
    if (i < 3 * 16384) {
        int which = i >> 14;
        int r = i & 16383;                           // r = k*128 + n
        int k = r >> 7, n = r & 127;
        const float* W = (which == 0) ? Qw : (which == 1) ? Kw : Vw;
        wt[((size_t)which << 14) + n * 128 + k] = f2bf(W[r]);
    }
}

// ---------------- fused hist (blocks [0,1024)) + proj (blocks [1024,+4688)) --------
// proj: barrier-free. One wave per (16-row tile, matrix, col-half): A from h rows,
// B direct from L2-resident wt (16 coalesced 16B loads), 16 MFMA, per-wave LDS
// epilogue for coalesced 16B qkv stores. 18750 independent waves.
__global__ __launch_bounds__(256) void proj_hist_kernel(
    const float* __restrict__ h_src, const float* __restrict__ h_dst,
    const unsigned short* __restrict__ wt,
    const float* __restrict__ Qb, const float* __restrict__ Kb, const float* __restrict__ Vb,
    unsigned short* __restrict__ qkv,
    const int* __restrict__ dst, int* __restrict__ counts8, int* __restrict__ rank)
{
    if (blockIdx.x < HIST_BLOCKS) {
        const int hb = blockIdx.x;
        const int c = hb >> 7;                       // chunked: 8 copies x 128 blocks
        int* cnt = counts8 + c * N_NODES;
        const int tid = hb * 256 + threadIdx.x;      // 0..262143
        const int e3 = tid + 786432;                 // valid iff tid < 13568
        const bool v3 = (e3 < E_EDGES);
        int d0 = dst[tid], d1 = dst[tid + 262144], d2 = dst[tid + 524288];
        int d3 = v3 ? dst[e3] : 0;
        int r0 = atomicAdd(&cnt[d0], 1);
        int r1 = atomicAdd(&cnt[d1], 1);
        int r2 = atomicAdd(&cnt[d2], 1);
        rank[tid] = r0; rank[tid + 262144] = r1; rank[tid + 524288] = r2;
        if (v3) rank[e3] = atomicAdd(&cnt[d3], 1);
        return;
    }

    __shared__ __align__(16) unsigned short smem[4][1152 + 8];   // per-wave stage, no sharing
    const int w  = threadIdx.x >> 6;
    const int l  = threadIdx.x & 63;
    const int gw = (blockIdx.x - HIST_BLOCKS) * 4 + w;
    if (gw >= PROJ_WAVES) return;

    const int rt    = gw / 6;
    const int unit  = gw - rt * 6;
    const int which = unit >> 1;                 // 0=Q 1=K 2=V
    const int half  = unit & 1;                  // col half 0/1
    const int lr = l & 15;                       // A-row in tile / B-col in frag
    const int kg = l >> 4;                       // k-group 0..3
    const int m_base = rt * 16;                  // exact: no bounds checks (50000 = 3125*16)

    const float* A  = (which == 0) ? h_dst : h_src;
    const float* ap = A + (size_t)(m_base + lr) * IN_DIM;

    // ---- A fragments: 8 float4 loads in flight, convert to bf16 ----
    short8v af[4];
    #pragma unroll
    for (int ks = 0; ks < 4; ++ks) {
        const int k0 = ks * 32 + kg * 8;
        float4 a0 = *(const float4*)&ap[k0];
        float4 a1 = *(const float4*)&ap[k0 + 4];
        af[ks][0] = (short)f2bf(a0.x); af[ks][1] = (short)f2bf(a0.y);
        af[ks][2] = (short)f2bf(a0.z); af[ks][3] = (short)f2bf(a0.w);
        af[ks][4] = (short)f2bf(a1.x); af[ks][5] = (short)f2bf(a1.y);
        af[ks][6] = (short)f2bf(a1.z); af[ks][7] = (short)f2bf(a1.w);
    }

    // ---- B fragments direct from wt (L2-resident), 16 independent loads + MFMA ----
    const unsigned short* W = wt + ((size_t)which << 14) + half * 64 * 128;
    float4v acc[4];
    #pragma unroll
    for (int i = 0; i < 4; ++i) acc[i] = (float4v)0.f;
    #pragma unroll
    for (int ks = 0; ks < 4; ++ks) {
        const int k0 = ks * 32 + kg * 8;
        #pragma unroll
        for (int nf = 0; nf < 4; ++nf) {
            short8v bf = *(const short8v*)&W[(size_t)(nf * 16 + lr) * 128 + k0];
            acc[nf] = __builtin_amdgcn_mfma_f32_16x16x32_bf16(af[ks], bf, acc[nf], 0, 0, 0);
        }
    }

    // ---- per-wave epilogue: LDS stage (own region, wave-internal wait only) ----
    const float* bias = (which == 0) ? Qb : (which == 1) ? Kb : Vb;
    unsigned short* stg = &smem[w][0];           // 16 rows x 72 shorts
    #pragma unroll
    for (int nf = 0; nf < 4; ++nf) {
        const float b = bias[half * 64 + nf * 16 + lr];
        #pragma unroll
        for (int r = 0; r < 4; ++r)
            stg[(kg * 4 + r) * 72 + nf * 16 + lr] = f2bf(acc[nf][r] + b);
    }
    #pragma unroll
    for (int i = 0; i < 2; ++i) {
        const int chunk = i * 64 + l;            // 128 chunks of 8 shorts = 16 rows x 64
        const int row = chunk >> 3;
        const int cc  = (chunk & 7) * 8;
        short8v v = *(const short8v*)&stg[row * 72 + cc];
        *(short8v*)&qkv[(size_t)(m_base + row) * 384 + which * 128 + half * 64 + cc] = v;
    }
}

// ---------------- offsets: per-node 8-copy prefix + wave scan -> begn/cnt/begc ------
__global__ __launch_bounds__(256) void offsets_kernel(const int* __restrict__ counts8,
                                                      int* __restrict__ begc,
                                                      int* __restrict__ begn,
                                                      int* __restrict__ cntn,
                                                      int* __restrict__ total) {
    int n = blockIdx.x * blockDim.x + threadIdx.x;
    int lane = threadIdx.x & 63;
    int pre[8];
    int s = 0;
    if (n < N_NODES) {
        #pragma unroll
        for (int c = 0; c < 8; ++c) {          // coalesced per copy
            int v = counts8[c * N_NODES + n];
            pre[c] = s; s += v;
        }
    }
    int incl = s;
    #pragma unroll
    for (int off = 1; off < 64; off <<= 1) {
        int y = __shfl_up(incl, off);
        if (lane >= off) incl += y;
    }
    int wsum = __shfl(incl, 63);
    int base = 0;
    if (lane == 0) base = atomicAdd(total, wsum);
    base = __shfl(base, 0);
    int b = base + incl - s;
    if (n < N_NODES) {
        begn[n] = b; cntn[n] = s;
        #pragma unroll
        for (int c = 0; c < 8; ++c) begc[c * N_NODES + n] = b + pre[c];
    }
}

// ---------------- scatter: atomic-free via begc + rank ----------------
// hist tid = e mod 2^18, hb = tid>>8, copy c = hb>>7 = (e & 262143) >> 15.
__global__ void scatter_kernel(const int* __restrict__ src, const int* __restrict__ dst,
                               const int* __restrict__ begc, const int* __restrict__ rank,
                               int* __restrict__ esrc) {
    int e = blockIdx.x * blockDim.x + threadIdx.x;
    if (e < E_EDGES) {
        int c = (e & 262143) >> 15;
        esrc[begc[c * N_NODES + dst[e]] + rank[e]] = src[e];
    }
}

// ---------------- aggregation: one wave per node; lane = (e-slot 0..3, chunk u 0..15) ----
// 4x unrolled: 16 edges / iteration, 4 idx + 8 row loads in flight.
__global__ __launch_bounds__(256) void agg_kernel(
    const unsigned short* __restrict__ qkv,
    const int* __restrict__ begp, const int* __restrict__ cntp,
    const int* __restrict__ esrc, float* __restrict__ out)
{
    int wave = (blockIdx.x * blockDim.x + threadIdx.x) >> 6;
    const int lane = threadIdx.x & 63;
    if (wave >= N_NODES) return;
    const int n = __builtin_amdgcn_readfirstlane(wave);
    const int e = lane >> 4;
    const int u = lane & 15;

    const uint4 qv = *(const uint4*)&qkv[(size_t)n * 384 + u * 8];
    const float q0 = bflo(qv.x), q1 = bfhi(qv.x), q2 = bflo(qv.y), q3 = bfhi(qv.y);
    const float q4 = bflo(qv.z), q5 = bfhi(qv.z), q6 = bflo(qv.w), q7 = bfhi(qv.w);

    const int b0 = begp[n], c0 = cntp[n], endp = b0 + c0;

    float a0=0.f,a1=0.f,a2=0.f,a3=0.f,a4=0.f,a5=0.f,a6=0.f,a7=0.f, z=0.f;

    for (int base = b0; base < endp; base += 16) {
        int idx[4];
        uint4 kk[4], vv[4];
        #pragma unroll
        for (int j = 0; j < 4; ++j) {
            idx[j] = base + j * 4 + e;
            const int s = esrc[min(idx[j], endp - 1)];
            const size_t ro = (size_t)s * 384;
            kk[j] = *(const uint4*)&qkv[ro + 128 + u * 8];
            vv[j] = *(const uint4*)&qkv[ro + 256 + u * 8];
        }
        #pragma unroll
        for (int j = 0; j < 4; ++j) {
            float d =      q0 * bflo(kk[j].x);
            d = fmaf(q1, bfhi(kk[j].x), d);
            d = fmaf(q2, bflo(kk[j].y), d);
            d = fmaf(q3, bfhi(kk[j].y), d);
            d = fmaf(q4, bflo(kk[j].z), d);
            d = fmaf(q5, bfhi(kk[j].z), d);
            d = fmaf(q6, bflo(kk[j].w), d);
            d = fmaf(q7, bfhi(kk[j].w), d);
            d += __shfl_xor(d, 1);
            float w = (idx[j] < endp) ? __expf(fminf(fmaxf(d * SQRT_D_INV, -5.f), 5.f)) : 0.f;
            z += w;
            a0 = fmaf(w, bflo(vv[j].x), a0);
            a1 = fmaf(w, bfhi(vv[j].x), a1);
            a2 = fmaf(w, bflo(vv[j].y), a2);
            a3 = fmaf(w, bfhi(vv[j].y), a3);
            a4 = fmaf(w, bflo(vv[j].z), a4);
            a5 = fmaf(w, bfhi(vv[j].z), a5);
            a6 = fmaf(w, bflo(vv[j].w), a6);
            a7 = fmaf(w, bfhi(vv[j].w), a7);
        }
    }

    #pragma unroll
    for (int mask = 16; mask <= 32; mask <<= 1) {
        z  += __shfl_xor(z, mask);
        a0 += __shfl_xor(a0, mask);
        a1 += __shfl_xor(a1, mask);
        a2 += __shfl_xor(a2, mask);
        a3 += __shfl_xor(a3, mask);
        a4 += __shfl_xor(a4, mask);
        a5 += __shfl_xor(a5, mask);
        a6 += __shfl_xor(a6, mask);
        a7 += __shfl_xor(a7, mask);
    }

    const float inv = 1.f / z;     // deg==0 -> 0*inf = NaN, matching reference 0/0
    if (e == 0) {
        *(float4*)&out[(size_t)n * HD + u * 8]     = make_float4(a0*inv, a1*inv, a2*inv, a3*inv);
        *(float4*)&out[(size_t)n * HD + u * 8 + 4] = make_float4(a4*inv, a5*inv, a6*inv, a7*inv);
    }
}

// ---------------- launcher ----------------
extern "C" void kernel_launch(void* const* d_in, const int* in_sizes, int n_in,
                              void* d_out, int out_size, void* d_ws, size_t ws_size,
                              hipStream_t stream) {
    const float* h_src = (const float*)d_in[0];
    const float* h_dst = (const float*)d_in[1];
    const int*   src   = (const int*)d_in[2];
    const int*   dst   = (const int*)d_in[3];
    const float* Qw    = (const float*)d_in[4];
    const float* Qb    = (const float*)d_in[5];
    const float* Kw    = (const float*)d_in[6];
    const float* Kb    = (const float*)d_in[7];
    const float* Vw    = (const float*)d_in[8];
    const float* Vb    = (const float*)d_in[9];
    float* out = (float*)d_out;

    char* ws = (char*)d_ws;
    const size_t qkv_bytes = (size_t)N_NODES * 384 * sizeof(unsigned short);  // 38.4 MB
    const size_t wt_bytes  = 3 * 128 * 128 * sizeof(unsigned short);          // 96 KB
    unsigned short* qkvp = (unsigned short*)(ws);
    unsigned short* wtp  = (unsigned short*)(ws + qkv_bytes);
    int* counts8 = (int*)(ws + qkv_bytes + wt_bytes);   // 8*N + 1 (total at [8N])
    int* total   = counts8 + 8 * N_NODES;
    int* begc    = counts8 + 8 * N_NODES + 1;           // 8*N
    int* begn    = begc + 8 * N_NODES;                  // N
    int* cntn    = begn + N_NODES;                      // N
    int* rank    = cntn + N_NODES;                      // E
    int* esrc    = rank + E_EDGES;                      // E

    wtr_init_kernel<<<392, 256, 0, stream>>>(Qw, Kw, Vw, wtp, counts8);

    proj_hist_kernel<<<HIST_BLOCKS + PROJ_BLOCKS, 256, 0, stream>>>(
        h_src, h_dst, wtp, Qb, Kb, Vb, qkvp, dst, counts8, rank);

    offsets_kernel<<<(N_NODES + 255) / 256, 256, 0, stream>>>(counts8, begc, begn, cntn, total);

    scatter_kernel<<<(E_EDGES + 255) / 256, 256, 0, stream>>>(src, dst, begc, rank, esrc);

    agg_kernel<<<(N_NODES * 64 + 255) / 256, 256, 0, stream>>>(qkvp, begn, cntn, esrc, out);
}

// Round 12
// 138.110 us; speedup vs baseline: 1.2659x; 1.2659x over previous
//
#include <hip/hip_runtime.h>
#include <hip/hip_bf16.h>
#include <math.h>

#define N_NODES 50000
#define E_EDGES 800000
#define IN_DIM  128
#define HD      128   // H*D
#define SQRT_D_INV 0.25f

#define HIST_BLOCKS 1024                    // hist first; tid stride 2^18; c=(e>>8)&7
#define PROJ_BLOCKS ((N_NODES + 63) / 64)   // 782

typedef __attribute__((ext_vector_type(8))) short short8v;
typedef __attribute__((ext_vector_type(4))) float float4v;

__device__ inline unsigned short f2bf(float x) {
    __hip_bfloat16 b = __float2bfloat16(x);
    return *reinterpret_cast<unsigned short*>(&b);
}
__device__ inline float bflo(unsigned int u) { return __uint_as_float(u << 16); }
__device__ inline float bfhi(unsigned int u) { return __uint_as_float(u & 0xffff0000u); }

// ---------------- W transpose+convert + zero counts8 ----------------
__global__ __launch_bounds__(256) void wtr_init_kernel(
    const float* __restrict__ Qw, const float* __restrict__ Kw, const float* __restrict__ Vw,
    unsigned short* __restrict__ wt, int* __restrict__ counts8)
{
    int i = blockIdx.x * 256 + threadIdx.x;          // 392*256 = 100352 threads
    for (int j = i; j <= 8 * N_NODES; j += 392 * 256) counts8[j] = 0;
    if (i < 3 * 16384) {
        int which = i >> 14;
        int r = i & 16383;                           // r = k*128 + n
        int k = r >> 7, n = r & 127;
        const float* W = (which == 0) ? Qw : (which == 1) ? Kw : Vw;
        wt[((size_t)which << 14) + n * 128 + k] = f2bf(W[r]);
    }
}

// ---------------- fused hist (blocks [0,1024)) + proj (blocks [1024,+782)) ----------
// proj: R6 shell. Key change: per K-step, preload 8 independent B-frags from LDS
// into registers (one lgkm wait), then 8 back-to-back MFMAs — kills the per-load
// round-trip serialization. Full 16-slot XOR swizzle on the W tile.
__global__ __launch_bounds__(256) void proj_hist_kernel(
    const float* __restrict__ h_src, const float* __restrict__ h_dst,
    const unsigned short* __restrict__ wt,
    const float* __restrict__ Qb, const float* __restrict__ Kb, const float* __restrict__ Vb,
    unsigned short* __restrict__ qkv,
    const int* __restrict__ dst, int* __restrict__ counts8, int* __restrict__ rank)
{
    if (blockIdx.x < HIST_BLOCKS) {
        const int c = blockIdx.x & 7;
        int* cnt = counts8 + c * N_NODES;
        int tid = blockIdx.x * 256 + threadIdx.x;
        for (int e = tid; e < E_EDGES; e += HIST_BLOCKS * 256)
            rank[e] = atomicAdd(&cnt[dst[e]], 1);
        return;
    }

    __shared__ __align__(16) unsigned short smem[16384];   // 32 KB W tile / epilogue overlay
    const int t  = threadIdx.x;
    const int wv = t >> 6;
    const int l  = t & 63;
    const int lr = l & 15;       // A-row within tile / B-col within frag
    const int kg = l >> 4;       // k-group 0..3
    const int m_base = (blockIdx.x - HIST_BLOCKS) * 64 + wv * 16;
    const int arow = min(m_base + lr, N_NODES - 1);

    const float* pd = h_dst + (size_t)arow * IN_DIM;
    const float* ps = h_src + (size_t)arow * IN_DIM;

    // A fragments for h_dst (Q) and h_src (K,V): 16 float4 loads in flight
    short8v afd[4], afs[4];
    #pragma unroll
    for (int ks = 0; ks < 4; ++ks) {
        const int k0 = ks * 32 + kg * 8;
        float4 a0 = *(const float4*)&pd[k0];
        float4 a1 = *(const float4*)&pd[k0 + 4];
        float4 b0 = *(const float4*)&ps[k0];
        float4 b1 = *(const float4*)&ps[k0 + 4];
        afd[ks][0] = (short)f2bf(a0.x); afd[ks][1] = (short)f2bf(a0.y);
        afd[ks][2] = (short)f2bf(a0.z); afd[ks][3] = (short)f2bf(a0.w);
        afd[ks][4] = (short)f2bf(a1.x); afd[ks][5] = (short)f2bf(a1.y);
        afd[ks][6] = (short)f2bf(a1.z); afd[ks][7] = (short)f2bf(a1.w);
        afs[ks][0] = (short)f2bf(b0.x); afs[ks][1] = (short)f2bf(b0.y);
        afs[ks][2] = (short)f2bf(b0.z); afs[ks][3] = (short)f2bf(b0.w);
        afs[ks][4] = (short)f2bf(b1.x); afs[ks][5] = (short)f2bf(b1.y);
        afs[ks][6] = (short)f2bf(b1.z); afs[ks][7] = (short)f2bf(b1.w);
    }

    unsigned short* stg = &smem[wv * 2176];    // 16 rows x 136 shorts, per-wave (overlay)

    #pragma unroll
    for (int phase = 0; phase < 3; ++phase) {
        if (phase) __syncthreads();            // prev epilogue reads done before restage
        // ---- cooperative W[phase] -> LDS, full swizzle: byte d -> d ^ (((d>>8)&15)<<4) ----
        const unsigned short* wsrc = wt + ((size_t)phase << 14);
        #pragma unroll
        for (int j = 0; j < 8; ++j) {
            const int selem = j * 2048 + t * 8;              // short index, 16B chunks
            const int d = selem * 2;                         // linear byte addr
            const int sd = d ^ (((d >> 8) & 15) << 4);       // swizzled byte addr
            *(short8v*)((char*)smem + sd) = *(const short8v*)&wsrc[selem];
        }
        __syncthreads();

        // ---- MFMA: per K-step, preload 8 B-frags (independent), then 8 MFMAs ----
        const short8v* aF = (phase == 0) ? afd : afs;
        float4v acc[8];
        #pragma unroll
        for (int i = 0; i < 8; ++i) acc[i] = (float4v)0.f;
        #pragma unroll
        for (int ks = 0; ks < 4; ++ks) {
            short8v bf[8];
            #pragma unroll
            for (int nf = 0; nf < 8; ++nf) {
                const int a = (nf * 16 + lr) * 256 + ks * 64 + kg * 16;
                const int sa = a ^ (lr << 4);                // (a>>8)&15 == lr
                bf[nf] = *(const short8v*)((const char*)smem + sa);
            }
            #pragma unroll
            for (int nf = 0; nf < 8; ++nf)
                acc[nf] = __builtin_amdgcn_mfma_f32_16x16x32_bf16(aF[ks], bf[nf], acc[nf], 0, 0, 0);
        }
        __syncthreads();                       // all waves done reading W

        // ---- epilogue: stage in own region (overlay), coalesced 16B stores ----
        const float* bias = (phase == 0) ? Qb : (phase == 1) ? Kb : Vb;
        #pragma unroll
        for (int nf = 0; nf < 8; ++nf) {
            const float b = bias[nf * 16 + lr];
            #pragma unroll
            for (int r = 0; r < 4; ++r)
                stg[(kg * 4 + r) * 136 + nf * 16 + lr] = f2bf(acc[nf][r] + b);
        }
        #pragma unroll
        for (int i = 0; i < 4; ++i) {
            const int chunk = i * 64 + l;      // 256 chunks of 8 shorts = 16 rows x 128
            const int row = chunk >> 4;
            const int c   = (chunk & 15) * 8;
            const int m = m_base + row;
            short8v v = *(const short8v*)&stg[row * 136 + c];
            if (m < N_NODES) *(short8v*)&qkv[(size_t)m * 384 + phase * 128 + c] = v;
        }
    }
}

// ---------------- offsets: per-node 8-copy prefix + wave scan -> begn/cnt/begc ------
__global__ __launch_bounds__(256) void offsets_kernel(const int* __restrict__ counts8,
                                                      int* __restrict__ begc,
                                                      int* __restrict__ begn,
                                                      int* __restrict__ cntn,
                                                      int* __restrict__ total) {
    int n = blockIdx.x * blockDim.x + threadIdx.x;
    int lane = threadIdx.x & 63;
    int pre[8];
    int s = 0;
    if (n < N_NODES) {
        #pragma unroll
        for (int c = 0; c < 8; ++c) {          // coalesced per copy
            int v = counts8[c * N_NODES + n];
            pre[c] = s; s += v;
        }
    }
    int incl = s;
    #pragma unroll
    for (int off = 1; off < 64; off <<= 1) {
        int y = __shfl_up(incl, off);
        if (lane >= off) incl += y;
    }
    int wsum = __shfl(incl, 63);
    int base = 0;
    if (lane == 0) base = atomicAdd(total, wsum);
    base = __shfl(base, 0);
    int b = base + incl - s;
    if (n < N_NODES) {
        begn[n] = b; cntn[n] = s;
        #pragma unroll
        for (int c = 0; c < 8; ++c) begc[c * N_NODES + n] = b + pre[c];
    }
}

// ---------------- scatter: atomic-free via begc + rank ----------------
// hist tid = e mod 2^18, hb = tid>>8, copy c = hb&7 = (e>>8)&7.
__global__ void scatter_kernel(const int* __restrict__ src, const int* __restrict__ dst,
                               const int* __restrict__ begc, const int* __restrict__ rank,
                               int* __restrict__ esrc) {
    int e = blockIdx.x * blockDim.x + threadIdx.x;
    if (e < E_EDGES) {
        int c = (e >> 8) & 7;
        esrc[begc[c * N_NODES + dst[e]] + rank[e]] = src[e];
    }
}

// ---------------- aggregation: one wave per node; lane = (e-slot 0..3, chunk u 0..15) ----
// 4x unrolled: 16 edges / iteration, 4 idx + 8 row loads in flight.
__global__ __launch_bounds__(256) void agg_kernel(
    const unsigned short* __restrict__ qkv,
    const int* __restrict__ begp, const int* __restrict__ cntp,
    const int* __restrict__ esrc, float* __restrict__ out)
{
    int wave = (blockIdx.x * blockDim.x + threadIdx.x) >> 6;
    const int lane = threadIdx.x & 63;
    if (wave >= N_NODES) return;
    const int n = __builtin_amdgcn_readfirstlane(wave);
    const int e = lane >> 4;
    const int u = lane & 15;

    const uint4 qv = *(const uint4*)&qkv[(size_t)n * 384 + u * 8];
    const float q0 = bflo(qv.x), q1 = bfhi(qv.x), q2 = bflo(qv.y), q3 = bfhi(qv.y);
    const float q4 = bflo(qv.z), q5 = bfhi(qv.z), q6 = bflo(qv.w), q7 = bfhi(qv.w);

    const int b0 = begp[n], c0 = cntp[n], endp = b0 + c0;

    float a0=0.f,a1=0.f,a2=0.f,a3=0.f,a4=0.f,a5=0.f,a6=0.f,a7=0.f, z=0.f;

    for (int base = b0; base < endp; base += 16) {
        int idx[4];
        uint4 kk[4], vv[4];
        #pragma unroll
        for (int j = 0; j < 4; ++j) {
            idx[j] = base + j * 4 + e;
            const int s = esrc[min(idx[j], endp - 1)];
            const size_t ro = (size_t)s * 384;
            kk[j] = *(const uint4*)&qkv[ro + 128 + u * 8];
            vv[j] = *(const uint4*)&qkv[ro + 256 + u * 8];
        }
        #pragma unroll
        for (int j = 0; j < 4; ++j) {
            float d =      q0 * bflo(kk[j].x);
            d = fmaf(q1, bfhi(kk[j].x), d);
            d = fmaf(q2, bflo(kk[j].y), d);
            d = fmaf(q3, bfhi(kk[j].y), d);
            d = fmaf(q4, bflo(kk[j].z), d);
            d = fmaf(q5, bfhi(kk[j].z), d);
            d = fmaf(q6, bflo(kk[j].w), d);
            d = fmaf(q7, bfhi(kk[j].w), d);
            d += __shfl_xor(d, 1);
            float w = (idx[j] < endp) ? __expf(fminf(fmaxf(d * SQRT_D_INV, -5.f), 5.f)) : 0.f;
            z += w;
            a0 = fmaf(w, bflo(vv[j].x), a0);
            a1 = fmaf(w, bfhi(vv[j].x), a1);
            a2 = fmaf(w, bflo(vv[j].y), a2);
            a3 = fmaf(w, bfhi(vv[j].y), a3);
            a4 = fmaf(w, bflo(vv[j].z), a4);
            a5 = fmaf(w, bfhi(vv[j].z), a5);
            a6 = fmaf(w, bflo(vv[j].w), a6);
            a7 = fmaf(w, bfhi(vv[j].w), a7);
        }
    }

    #pragma unroll
    for (int mask = 16; mask <= 32; mask <<= 1) {
        z  += __shfl_xor(z, mask);
        a0 += __shfl_xor(a0, mask);
        a1 += __shfl_xor(a1, mask);
        a2 += __shfl_xor(a2, mask);
        a3 += __shfl_xor(a3, mask);
        a4 += __shfl_xor(a4, mask);
        a5 += __shfl_xor(a5, mask);
        a6 += __shfl_xor(a6, mask);
        a7 += __shfl_xor(a7, mask);
    }

    const float inv = 1.f / z;     // deg==0 -> 0*inf = NaN, matching reference 0/0
    if (e == 0) {
        *(float4*)&out[(size_t)n * HD + u * 8]     = make_float4(a0*inv, a1*inv, a2*inv, a3*inv);
        *(float4*)&out[(size_t)n * HD + u * 8 + 4] = make_float4(a4*inv, a5*inv, a6*inv, a7*inv);
    }
}

// ---------------- launcher ----------------
extern "C" void kernel_launch(void* const* d_in, const int* in_sizes, int n_in,
                              void* d_out, int out_size, void* d_ws, size_t ws_size,
                              hipStream_t stream) {
    const float* h_src = (const float*)d_in[0];
    const float* h_dst = (const float*)d_in[1];
    const int*   src   = (const int*)d_in[2];
    const int*   dst   = (const int*)d_in[3];
    const float* Qw    = (const float*)d_in[4];
    const float* Qb    = (const float*)d_in[5];
    const float* Kw    = (const float*)d_in[6];
    const float* Kb    = (const float*)d_in[7];
    const float* Vw    = (const float*)d_in[8];
    const float* Vb    = (const float*)d_in[9];
    float* out = (float*)d_out;

    char* ws = (char*)d_ws;
    const size_t qkv_bytes = (size_t)N_NODES * 384 * sizeof(unsigned short);  // 38.4 MB
    const size_t wt_bytes  = 3 * 128 * 128 * sizeof(unsigned short);          // 96 KB
    unsigned short* qkvp = (unsigned short*)(ws);
    unsigned short* wtp  = (unsigned short*)(ws + qkv_bytes);
    int* counts8 = (int*)(ws + qkv_bytes + wt_bytes);   // 8*N + 1 (total at [8N])
    int* total   = counts8 + 8 * N_NODES;
    int* begc    = counts8 + 8 * N_NODES + 1;           // 8*N
    int* begn    = begc + 8 * N_NODES;                  // N
    int* cntn    = begn + N_NODES;                      // N
    int* rank    = cntn + N_NODES;                      // E
    int* esrc    = rank + E_EDGES;                      // E

    wtr_init_kernel<<<392, 256, 0, stream>>>(Qw, Kw, Vw, wtp, counts8);

    proj_hist_kernel<<<HIST_BLOCKS + PROJ_BLOCKS, 256, 0, stream>>>(
        h_src, h_dst, wtp, Qb, Kb, Vb, qkvp, dst, counts8, rank);

    offsets_kernel<<<(N_NODES + 255) / 256, 256, 0, stream>>>(counts8, begc, begn, cntn, total);

    scatter_kernel<<<(E_EDGES + 255) / 256, 256, 0, stream>>>(src, dst, begc, rank, esrc);

    agg_kernel<<<(N_NODES * 64 + 255) / 256, 256, 0, stream>>>(qkvp, begn, cntn, esrc, out);
}